// Round 9
// baseline (111.306 us; speedup 1.0000x reference)
//
#include <hip/hip_runtime.h>
#include <math.h>

// SSIM on MI355X, round 9: occupancy experiment. Same algorithm as R8
// (rolling-window separable conv, packed float2 channels, wave-private LDS,
// no __syncthreads) but restructured for >=7 waves/SIMD residency:
// 128-thread blocks (2 waves), 4-row strips (small register window),
// 5.5 KB LDS/wave, sequential per-channel hconv to cap VGPR pressure.

#define WI 320
#define HI 320
#define NI 64
#define TWO 58                  // output cols per x-tile (64 loaded incl halo)
#define GXD 6
#define SROWS 16                // output rows per wave (4 strips of 4)
#define ITERS 4
#define WPB 2                   // waves per block
#define RPB (WPB * SROWS)       // 32 rows per block
#define GYD (HI / RPB)          // 10
#define NBLK (GXD * GYD * NI)   // 3840
#define NPART (NBLK * WPB)      // 7680 partials
#define NPIX ((double)NI * WI * HI)

// per-wave LDS slab (dword offsets). mu/sq rows: 64 used pairs + pad, stride
// 136 dwords; xy rows: stride 68. total 1360 dwords (5440 B) per wave.
#define MU_OFF 0
#define SQ_OFF 544
#define XY_OFF 1088
#define WAVE_LDS 1368           // + pad for b128 tail reads

typedef float v2 __attribute__((ext_vector_type(2)));
typedef float v4 __attribute__((ext_vector_type(4)));

struct W7 { float w[7]; };

// pair p (0..9) from 5 contiguous v4 regs (p constant after unroll)
__device__ __forceinline__ v2 pget5(const v4* t, int p) {
    v4 q = t[p >> 1];
    return (p & 1) ? (v2){q.z, q.w} : (v2){q.x, q.y};
}
// scalar p (0..9) from 3 contiguous v4 regs
__device__ __forceinline__ float sget3(const v4* t, int p) {
    v4 q = t[p >> 2];
    switch (p & 3) { case 0: return q.x; case 1: return q.y; case 2: return q.z; default: return q.w; }
}

__global__ __launch_bounds__(WPB * 64) void ssim_kernel(
    const float* __restrict__ X, const float* __restrict__ Y,
    W7 wv, float* __restrict__ partial)
{
    __shared__ __align__(16) float lds_all[WPB * WAVE_LDS];

    const int tid  = threadIdx.x;
    const int lane = tid & 63;
    const int wid  = tid >> 6;
    float* lds = lds_all + wid * WAVE_LDS;

    const int x0 = blockIdx.x * TWO;
    const int y0 = blockIdx.y * RPB + wid * SROWS;
    const float* __restrict__ Xn = X + (size_t)blockIdx.z * (WI * HI);
    const float* __restrict__ Yn = Y + (size_t)blockIdx.z * (WI * HI);

    // vconv mapping: lane = loaded col (0..63)
    const int  gx   = x0 + lane - 3;
    const bool xok  = (unsigned)gx < (unsigned)WI;
    const int  gxc  = min(max(gx, 0), WI - 1);
    const int  maxc = min(TWO, WI - x0);

    // hconv mapping: 60 lanes -> (row 0..3, col group c0 in {0,4,..,56})
    const bool act  = lane < 60;
    const int  hrow = lane / 15;
    const int  c0   = (lane % 15) * 4;

    const float C1 = 0.0004f, C2 = 0.0036f, COVN = 49.f / 48.f;

    // rolling 10-row window of (X,Y); prime rows y0-3 .. y0+2
    v2 win[10];
#pragma unroll
    for (int k = 0; k < 6; ++k) {
        const int gy  = y0 - 3 + k;
        const bool ok = xok && ((unsigned)gy < (unsigned)HI);
        const int gyc = min(max(gy, 0), HI - 1);
        const size_t idx = (size_t)gyc * WI + gxc;
        v2 t; t.x = Xn[idx]; t.y = Yn[idx];
        win[k] = ok ? t : (v2){0.f, 0.f};
    }

    float lsum = 0.f;
#pragma unroll 1
    for (int it = 0; it < ITERS; ++it) {
        const int base = y0 + 4 * it;

        // ---- load 4 new rows (base+3 .. base+6) ----
#pragma unroll
        for (int k = 0; k < 4; ++k) {
            const int gy  = base + 3 + k;
            const bool ok = xok && ((unsigned)gy < (unsigned)HI);
            const int gyc = min(max(gy, 0), HI - 1);
            const size_t idx = (size_t)gyc * WI + gxc;
            v2 t; t.x = Xn[idx]; t.y = Yn[idx];
            win[6 + k] = ok ? t : (v2){0.f, 0.f};
        }

        // ---- vertical 7-tap: 4 rows x {mu2, sq2, xy} ----
        v2 amu[4], asq[4]; float axy[4];
#pragma unroll
        for (int r = 0; r < 4; ++r) { amu[r] = (v2){0.f,0.f}; asq[r] = (v2){0.f,0.f}; axy[r] = 0.f; }
#pragma unroll
        for (int k = 0; k < 10; ++k) {
            const v2 v = win[k];
            const v2 sq = v * v;
            const float pxy = v.x * v.y;
#pragma unroll
            for (int r = 0; r < 4; ++r) {
                const int d = k - r;               // compile-time predicate
                if (d >= 0 && d < 7) {
                    const float w = wv.w[d];
                    amu[r] += w * v;
                    asq[r] += w * sq;
                    axy[r] += w * pxy;
                }
            }
        }

        // ---- LDS: 12 writes (b64 pairs + b32), col = lane ----
#pragma unroll
        for (int r = 0; r < 4; ++r) {
            *(v2*)&lds[MU_OFF + r * 136 + 2 * lane] = amu[r];
            *(v2*)&lds[SQ_OFF + r * 136 + 2 * lane] = asq[r];
            lds[XY_OFF + r * 68 + lane] = axy[r];
        }
        __builtin_amdgcn_wave_barrier();   // wave-synchronous; lgkmcnt orders data

        // ---- horizontal 7-tap + SSIM: 4 outputs (hrow, c0..c0+3) ----
        if (act) {
            v2 mmu[4], msq[4]; float mxy[4];
#pragma unroll
            for (int j = 0; j < 4; ++j) { mmu[j] = (v2){0.f,0.f}; msq[j] = (v2){0.f,0.f}; mxy[j] = 0.f; }
            {
                v4 t[5];
#pragma unroll
                for (int q = 0; q < 5; ++q)
                    t[q] = *(const v4*)&lds[MU_OFF + hrow * 136 + 2 * c0 + 4 * q];
#pragma unroll
                for (int j = 0; j < 4; ++j)
#pragma unroll
                    for (int d = 0; d < 7; ++d)
                        mmu[j] += wv.w[d] * pget5(t, j + d);
            }
            {
                v4 t[5];
#pragma unroll
                for (int q = 0; q < 5; ++q)
                    t[q] = *(const v4*)&lds[SQ_OFF + hrow * 136 + 2 * c0 + 4 * q];
#pragma unroll
                for (int j = 0; j < 4; ++j)
#pragma unroll
                    for (int d = 0; d < 7; ++d)
                        msq[j] += wv.w[d] * pget5(t, j + d);
            }
            {
                v4 u[3];
#pragma unroll
                for (int q = 0; q < 3; ++q)
                    u[q] = *(const v4*)&lds[XY_OFF + hrow * 68 + c0 + 4 * q];
#pragma unroll
                for (int j = 0; j < 4; ++j)
#pragma unroll
                    for (int d = 0; d < 7; ++d)
                        mxy[j] += wv.w[d] * sget3(u, j + d);
            }
#pragma unroll
            for (int j = 0; j < 4; ++j) {
                const v2 mu   = mmu[j];
                const v2 musq = mu * mu;                   // (mx^2, my^2)
                const float pm  = mu.x * mu.y;
                const v2 sig  = (msq[j] - musq) * COVN;    // (vx, vy)
                const float vxy = (mxy[j] - pm) * COVN;
                const float num = (2.f * pm + C1) * (2.f * vxy + C2);
                const float den = (musq.x + musq.y + C1) * (sig.x + sig.y + C2);
                lsum += (c0 + j < maxc) ? num * __builtin_amdgcn_rcpf(den) : 0.f;
            }
        }

        // ---- roll window down 4 rows ----
#pragma unroll
        for (int k = 0; k < 6; ++k) win[k] = win[k + 4];
    }

    // ---- wave reduction -> per-wave partial ----
#pragma unroll
    for (int off = 32; off > 0; off >>= 1)
        lsum += __shfl_down(lsum, off, 64);
    if (lane == 0) {
        const int bid = ((blockIdx.z * GYD + blockIdx.y) * GXD + blockIdx.x) * WPB + wid;
        partial[bid] = lsum;
    }
}

__global__ __launch_bounds__(256) void ssim_finalize(
    const float* __restrict__ partial, float* __restrict__ out)
{
    __shared__ double ws[4];
    const int tid = threadIdx.x;
    double s = 0.0;
    for (int i = tid; i < NPART; i += 256) s += (double)partial[i];
#pragma unroll
    for (int off = 32; off > 0; off >>= 1)
        s += __shfl_down(s, off, 64);
    if ((tid & 63) == 0) ws[tid >> 6] = s;
    __syncthreads();
    if (tid == 0)
        out[0] = (float)(1.0 - ((ws[0] + ws[1]) + (ws[2] + ws[3])) / NPIX);
}

extern "C" void kernel_launch(void* const* d_in, const int* in_sizes, int n_in,
                              void* d_out, int out_size, void* d_ws, size_t ws_size,
                              hipStream_t stream) {
    const float* X = (const float*)d_in[0];
    const float* Y = (const float*)d_in[1];
    // Exact 1D Gaussian weights in fp64 (7x7 window = outer product).
    W7 wv;
    {
        double gk[7], s = 0.0;
        for (int i = 0; i < 7; ++i) {
            double x = (double)(i - 3);
            gk[i] = exp(-(x * x) / (2.0 * 1.5 * 1.5));
            s += gk[i];
        }
        for (int i = 0; i < 7; ++i) wv.w[i] = (float)(gk[i] / s);
    }

    float* partial = (float*)d_ws;   // 7680 floats, fully written every launch

    dim3 grid(GXD, GYD, NI);         // 6 x 10 x 64 = 3840 blocks, 128 thr
    ssim_kernel<<<grid, WPB * 64, 0, stream>>>(X, Y, wv, partial);
    ssim_finalize<<<1, 256, 0, stream>>>(partial, (float*)d_out);
}